// Round 1
// baseline (130.612 us; speedup 1.0000x reference)
//
#include <hip/hip_runtime.h>

#define TPB 1024
#define NW (TPB / 64)
#define NCOLS 16384
#define F4PT (NCOLS / 4 / TPB)   // 4 float4 per thread
#define NELEM (F4PT * 4)         // 16 elements per thread
#define BINS1 4096               // pass1: key >> 19 (12 bits)
#define TIE_CAP 2048

__device__ __forceinline__ unsigned keyOf(float f) {
    return __float_as_uint(f) & 0x7fffffffu;
}

// Block-wide descending (suffix) select over hist[NBINS]:
// finds bin b s.t. sum(hist[b..NBINS-1]) first reaches >= Krem, scanning from top.
// Requires hist ready (caller synced). Ends with __syncthreads().
// bc[0]=cut bin, bc[1]=remaining quota within bin, bc[2]=count in bin.
template <int NBINS>
__device__ void suffix_select(const unsigned* hist, unsigned Krem,
                              unsigned* wsums, unsigned* bc) {
    const int t = threadIdx.x;
    const int lane = t & 63;
    const int wave = t >> 6;
    constexpr int CH = (NBINS + TPB - 1) / TPB;
    const int base = t * CH;
    unsigned hv[CH];
    unsigned c = 0;
#pragma unroll
    for (int i = 0; i < CH; ++i) {
        hv[i] = (base + i < NBINS) ? hist[base + i] : 0u;
        c += hv[i];
    }
    // in-wave inclusive suffix scan (Hillis-Steele via shfl_down)
    unsigned s = c;
#pragma unroll
    for (int off = 1; off < 64; off <<= 1) {
        unsigned o = __shfl_down(s, off);
        if (lane + off < 64) s += o;
    }
    if (lane == 0) wsums[wave] = s;   // wave total
    __syncthreads();
    if (wave == 0) {
        unsigned ws = (lane < NW) ? wsums[lane] : 0u;
        unsigned ss = ws;
#pragma unroll
        for (int off = 1; off < 64; off <<= 1) {
            unsigned o = __shfl_down(ss, off);
            if (lane + off < 64) ss += o;
        }
        if (lane < NW) wsums[lane] = ss;  // inclusive suffix over waves
    }
    __syncthreads();
    // elements in bins strictly above this thread's chunk
    unsigned gts = ((wave + 1 < NW) ? wsums[wave + 1] : 0u) + (s - c);
    if (gts < Krem && gts + c >= Krem) {   // exactly one thread brackets the cut
        unsigned cum = gts;
#pragma unroll
        for (int i = CH - 1; i >= 0; --i) {
            unsigned h = hv[i];
            cum += h;
            if (cum >= Krem) {
                bc[0] = (unsigned)(base + i);
                bc[1] = Krem - (cum - h);   // quota within the cut bin (>=1)
                bc[2] = h;                  // population of the cut bin
                break;
            }
        }
    }
    __syncthreads();
}

__global__ __launch_bounds__(TPB) void topk_mask_kernel(
        const float* __restrict__ x, const int* __restrict__ kp,
        float* __restrict__ out) {
    __shared__ unsigned hist[BINS1];
    __shared__ unsigned wsums[NW];
    __shared__ unsigned bc[3];
    __shared__ unsigned tieIdx[TIE_CAP];
    __shared__ unsigned tieCnt;

    const int t = threadIdx.x;
    const unsigned K = (unsigned)(*kp);
    const size_t row = blockIdx.x;
    const float4* xr = reinterpret_cast<const float4*>(x) + row * (NCOLS / 4);
    float4* orow = reinterpret_cast<float4*>(out) + row * (NCOLS / 4);

    // Load entire row into registers once; hold through all passes.
    float vals[NELEM];
#pragma unroll
    for (int i = 0; i < F4PT; ++i) {
        float4 tmp = xr[t + i * TPB];
        vals[4 * i + 0] = tmp.x;
        vals[4 * i + 1] = tmp.y;
        vals[4 * i + 2] = tmp.z;
        vals[4 * i + 3] = tmp.w;
    }

    // ---------- pass 1: top 12 bits ----------
    for (int i = t; i < BINS1; i += TPB) hist[i] = 0u;
    __syncthreads();
#pragma unroll
    for (int e = 0; e < NELEM; ++e) {
        unsigned key = keyOf(vals[e]);
        atomicAdd(&hist[key >> 19], 1u);
    }
    __syncthreads();
    suffix_select<BINS1>(hist, K, wsums, bc);
    const unsigned cut1 = bc[0];
    const unsigned r1 = bc[1];

    // ---------- pass 2: next 10 bits ----------
    for (int i = t; i < BINS1; i += TPB) hist[i] = 0u;
    __syncthreads();
#pragma unroll
    for (int e = 0; e < NELEM; ++e) {
        unsigned key = keyOf(vals[e]);
        if ((key >> 19) == cut1) atomicAdd(&hist[(key >> 9) & 1023u], 1u);
    }
    __syncthreads();
    suffix_select<1024>(hist, r1, wsums, bc);
    const unsigned cut2 = bc[0];
    const unsigned r2 = bc[1];
    const unsigned pfx2 = (cut1 << 10) | cut2;

    // ---------- pass 3: low 9 bits ----------
    for (int i = t; i < BINS1; i += TPB) hist[i] = 0u;
    __syncthreads();
#pragma unroll
    for (int e = 0; e < NELEM; ++e) {
        unsigned key = keyOf(vals[e]);
        if ((key >> 9) == pfx2) atomicAdd(&hist[key & 511u], 1u);
    }
    __syncthreads();
    suffix_select<512>(hist, r2, wsums, bc);
    const unsigned cut3 = bc[0];
    const unsigned r = bc[1];     // how many elements equal to T we may keep
    const unsigned E = bc[2];     // how many elements equal T
    const unsigned T = (pfx2 << 9) | cut3;   // exact K-th largest abs key

    // ---------- rare tie fix: keep the r lowest-index equals (jax top_k order) ----------
    if (E > r) {                   // block-uniform branch
        if (t == 0) tieCnt = 0u;
        __syncthreads();
#pragma unroll
        for (int e = 0; e < NELEM; ++e) {
            if (keyOf(vals[e]) == T) {
                unsigned idx = (unsigned)((t + (e >> 2) * TPB) * 4 + (e & 3));
                unsigned p = atomicAdd(&tieCnt, 1u);
                if (p < TIE_CAP) tieIdx[p] = idx;
            }
        }
        __syncthreads();
        unsigned cnt = tieCnt < TIE_CAP ? tieCnt : TIE_CAP;
#pragma unroll
        for (int e = 0; e < NELEM; ++e) {
            if (keyOf(vals[e]) == T) {
                unsigned idx = (unsigned)((t + (e >> 2) * TPB) * 4 + (e & 3));
                unsigned rank = 0;
                for (unsigned p = 0; p < cnt; ++p) rank += (tieIdx[p] < idx) ? 1u : 0u;
                if (rank >= r) vals[e] = 0.0f;   // dropped: key becomes 0 < T
            }
        }
        __syncthreads();
    }

    // ---------- write: keep iff |x| key >= T ----------
#pragma unroll
    for (int i = 0; i < F4PT; ++i) {
        float4 o;
        o.x = (keyOf(vals[4 * i + 0]) >= T) ? vals[4 * i + 0] : 0.0f;
        o.y = (keyOf(vals[4 * i + 1]) >= T) ? vals[4 * i + 1] : 0.0f;
        o.z = (keyOf(vals[4 * i + 2]) >= T) ? vals[4 * i + 2] : 0.0f;
        o.w = (keyOf(vals[4 * i + 3]) >= T) ? vals[4 * i + 3] : 0.0f;
        orow[t + i * TPB] = o;
    }
}

extern "C" void kernel_launch(void* const* d_in, const int* in_sizes, int n_in,
                              void* d_out, int out_size, void* d_ws, size_t ws_size,
                              hipStream_t stream) {
    const float* x = (const float*)d_in[0];
    const int* kp = (const int*)d_in[1];
    float* out = (float*)d_out;
    const int rows = in_sizes[0] / NCOLS;   // 4096
    topk_mask_kernel<<<rows, TPB, 0, stream>>>(x, kp, out);
}